// Round 1
// 82.136 us; speedup vs baseline: 1.0432x; 1.0432x over previous
//
#include <hip/hip_runtime.h>
#include <hip/hip_bf16.h>

// NT-Xent loss, N=4096, Z=128, T=0.5.
//
// Round 4: scratch matrix in MFMA-FRAGMENT ORDER -> every A/B fragment load
// is a coalesced global_load_dwordx4 (1 KB/wave-load).
//   pack[(G*4 + ks)*64 + q*16 + n] (16B granules) = rows G*16+n,
//   k in [ks*32+q*8, +8).
// Rounds 5/6: symmetry with tiny (2-step) blocks regressed: latency-bound.
// Round 7: full matrix, 64-row waves (afrag[4][4]), 32-col half-steps with
// register-double-buffered B. 512 blocks = 2/CU, ~40 us for k_simsum.
// Round 8: SYMMETRY, done right. e_ij = e_ji, so each strictly-upper tile
// feeds denom[row] (row path) AND denom[col] (col path: per-lane partial
// over the lane's 16 rows, 2 shfls across q, atomic per 16-col tile).
// Diagonal-band tiles stay row-only with the self-mask. Work is balanced
// as 4224 upper-triangle 32-col half-step units, strip-partitioned over
// EXACTLY 512 blocks (8-9 units each, all co-resident, no 2-round tail
// that a 528-tile grid would hit). Round-7 inner structure otherwise
// unchanged. Expect ~0.56x on k_simsum (MFMA, L1 fragment BW, and exp2
// all halve together).
//
//  k_normalize: row-normalize (fp32), quantize bf16 scaled by
//               QS = sqrt(2*log2(e)) (folds 1/T=2 and exp->exp2), write in
//               fragment order; exact fp32 pair-cosines pos[4096]; zero denom.
//  k_simsum:    denom[i] = sum_{j!=i} exp(2*sim_ij), triangle + mirror.
//  k_finish:    out = (sum_i log denom_i - 4 * sum_p pos_p) / 8192

#define N_PAIRS 4096
#define ZDIM    128
#define NROWS   8192
#define QS 1.6986437717f   // sqrt(2 * log2(e))

typedef __bf16 bf16x8 __attribute__((ext_vector_type(8)));
typedef float  floatx4 __attribute__((ext_vector_type(4)));

__global__ __launch_bounds__(256) void k_normalize(
    const float* __restrict__ z1, const float* __restrict__ z2,
    __hip_bfloat16* __restrict__ pack, float* __restrict__ pos,
    float* __restrict__ denom)
{
    const int zi = blockIdx.x * 256 + threadIdx.x;   // grid 1024 blocks; 32 zero denom
    if (zi < NROWS) denom[zi] = 0.0f;

    const int w = threadIdx.x >> 6;
    const int lane = threadIdx.x & 63;
    const int p = blockIdx.x * 4 + w;            // pair index, < 4096
    const float2 a = ((const float2*)(z1 + (size_t)p * ZDIM))[lane];
    const float2 b = ((const float2*)(z2 + (size_t)p * ZDIM))[lane];
    float s1 = a.x * a.x + a.y * a.y;
    float s2 = b.x * b.x + b.y * b.y;
    float d  = a.x * b.x + a.y * b.y;
    #pragma unroll
    for (int off = 1; off < 64; off <<= 1) {
        s1 += __shfl_xor(s1, off, 64);
        s2 += __shfl_xor(s2, off, 64);
        d  += __shfl_xor(d,  off, 64);
    }
    const float n1 = fmaxf(sqrtf(s1), 1e-8f);
    const float n2 = fmaxf(sqrtf(s2), 1e-8f);
    const float i1 = 1.0f / n1, i2 = 1.0f / n2;
    const float q1 = i1 * QS, q2 = i2 * QS;
    float2 na; na.x = a.x * q1; na.y = a.y * q1;
    float2 nb; nb.x = b.x * q2; nb.y = b.y * q2;

    // lane holds elements e0=2*lane, e0+1 of its row:
    //   ks = lane>>4 ; q = (lane>>2)&3 ; j = (lane&3)*2
    // pack elem idx for row r: ((r>>4)*4 + ks)*512 + q*128 + (r&15)*8 + j
    const int ks = lane >> 4;
    const int qq = (lane >> 2) & 3;
    const int jj = (lane & 3) * 2;
    const int r1 = p, r2 = p + N_PAIRS;
    const size_t i1e = ((size_t)((r1 >> 4) * 4 + ks)) * 512 + qq * 128 + (r1 & 15) * 8 + jj;
    const size_t i2e = ((size_t)((r2 >> 4) * 4 + ks)) * 512 + qq * 128 + (r2 & 15) * 8 + jj;
    *(__hip_bfloat162*)(pack + i1e) = __float22bfloat162_rn(na);
    *(__hip_bfloat162*)(pack + i2e) = __float22bfloat162_rn(nb);
    if (lane == 0) pos[p] = d * i1 * i2;
}

// Upper-triangle strip schedule.
// Unit = 256 rows (one row-tile rt) x 32 cols. Row rt contributes units
// ur = 0..(255-8*rt); col = rt*256 + ur*32. Units ur<8 are the diagonal
// 256x256 band: row-only accumulation + self-mask (both orderings of a
// within-band pair occur inside the band). Units ur>=8 are strictly upper:
// accumulate row path AND mirrored col path.
// Global unit count: sum_rt (256-8*rt) = 4224 = 512 blocks * 8.25.
// Block b handles units [33b/4, 33(b+1)/4) -- 8 or 9 units, contiguous,
// crossing a row-tile boundary (A-frag reload) in only ~31 blocks.
__global__ __launch_bounds__(256) void k_simsum(
    const __hip_bfloat16* __restrict__ pack, float* __restrict__ denom)
{
    const int tid  = threadIdx.x;
    const int lane = tid & 63;
    const int w    = tid >> 6;
    const int q    = lane >> 4;         // quad 0..3
    const int l16  = lane & 15;

    const int b  = blockIdx.x;
    int u        = (33 * b) >> 2;       // first global unit
    const int u1 = (33 * b + 33) >> 2;  // one past last

    // S(rt) = 256*rt - 4*rt*(rt-1); find rt with S(rt) <= u < S(rt+1)
    int rt = 0, snext = 256;            // snext = S(rt+1)
    while (u >= snext) { ++rt; snext += 256 - 8 * rt; }

    bf16x8 bufA[4][2], bufB[4][2];

    auto loadB = [&](bf16x8 (&buf)[4][2], int col) {
        const __hip_bfloat16* bp = pack + (size_t)col * 128 + lane * 8;
        #pragma unroll
        for (int ks = 0; ks < 4; ++ks)      // ks-major: first MFMA waits least
            #pragma unroll
            for (int nt = 0; nt < 2; ++nt)
                buf[ks][nt] = *(const bf16x8*)(bp + nt * 2048 + ks * 512);
    };

    while (u < u1) {                    // per row-tile segment (1-2 iterations)
        const int srt  = snext - (256 - 8 * rt);   // S(rt)
        const int uend = (u1 < snext) ? u1 : snext;
        const int rowb = rt * 256 + w * 64;

        // persistent A fragments: wave's 64 rows x full K=128 (64 VGPRs)
        const __hip_bfloat16* Abase = pack + (size_t)rowb * 128 + lane * 8;
        bf16x8 afrag[4][4];              // [mt][ks]
        #pragma unroll
        for (int mt = 0; mt < 4; ++mt)
            #pragma unroll
            for (int ks = 0; ks < 4; ++ks)
                afrag[mt][ks] = *(const bf16x8*)(Abase + mt * 2048 + ks * 512);

        float rowsum[4][4];              // [mt][r]
        #pragma unroll
        for (int mt = 0; mt < 4; ++mt)
            #pragma unroll
            for (int r = 0; r < 4; ++r) rowsum[mt][r] = 0.0f;

        auto compute = [&](bf16x8 (&buf)[4][2], int ur) {
            const int  col  = rt * 256 + ur * 32;
            const bool band = (ur < 8);            // wave-uniform
            floatx4 acc[4][2];
            #pragma unroll
            for (int mt = 0; mt < 4; ++mt)
                #pragma unroll
                for (int nt = 0; nt < 2; ++nt) {
                    acc[mt][nt].x = 0.f; acc[mt][nt].y = 0.f;
                    acc[mt][nt].z = 0.f; acc[mt][nt].w = 0.f;
                }
            #pragma unroll
            for (int ks = 0; ks < 4; ++ks)
                #pragma unroll
                for (int mt = 0; mt < 4; ++mt)
                    #pragma unroll
                    for (int nt = 0; nt < 2; ++nt)
                        acc[mt][nt] = __builtin_amdgcn_mfma_f32_16x16x32_bf16(
                            afrag[mt][ks], buf[ks][nt], acc[mt][nt], 0, 0, 0);
            // fused epilogue. C/D layout: col = l16, row = q*4 + r (m89/m91).
            float cp0 = 0.0f, cp1 = 0.0f;   // col-path partials per nt tile
            #pragma unroll
            for (int mt = 0; mt < 4; ++mt) {
                const int rowtb = rowb + mt * 16;
                #pragma unroll
                for (int nt = 0; nt < 2; ++nt) {
                    const int coltb = col + nt * 16;
                    if (band && rowtb == coltb) {   // wave-uniform: diag tile
                        #pragma unroll
                        for (int r = 0; r < 4; ++r) {
                            const float e = __builtin_amdgcn_exp2f(acc[mt][nt][r]);
                            rowsum[mt][r] += (l16 == q * 4 + r) ? 0.0f : e;
                        }
                    } else {
                        #pragma unroll
                        for (int r = 0; r < 4; ++r) {
                            const float e = __builtin_amdgcn_exp2f(acc[mt][nt][r]);
                            rowsum[mt][r] += e;
                            if (!band) { if (nt == 0) cp0 += e; else cp1 += e; }
                        }
                    }
                }
            }
            if (!band) {
                // col path: lane's partial covers rows {mt*16 + q*4 + r} of
                // col l16; reduce across q -> all 64 wave rows, then mirror
                // into denom[col].
                cp0 += __shfl_xor(cp0, 16, 64);
                cp0 += __shfl_xor(cp0, 32, 64);
                cp1 += __shfl_xor(cp1, 16, 64);
                cp1 += __shfl_xor(cp1, 32, 64);
                if (q == 0) {
                    atomicAdd(&denom[col + l16], cp0);
                    atomicAdd(&denom[col + 16 + l16], cp1);
                }
            }
        };

        // double-buffered sweep over units [u, uend) of this row-tile
        int ur        = u - srt;
        const int urn = uend - srt;
        loadB(bufA, rt * 256 + ur * 32);
        while (ur + 2 <= urn) {
            loadB(bufB, rt * 256 + (ur + 1) * 32);
            compute(bufA, ur);
            int nx = ur + 2;
            if (nx >= urn) nx = urn - 1;     // clamp: preloads odd tail unit
            loadB(bufA, rt * 256 + nx * 32);
            compute(bufB, ur + 1);
            ur += 2;
        }
        if (ur < urn) compute(bufA, ur);     // odd tail (bufA holds its cols)

        // row-sum flush: reduce across the 16 lanes holding the same row
        #pragma unroll
        for (int mt = 0; mt < 4; ++mt)
            #pragma unroll
            for (int r = 0; r < 4; ++r) {
                float s = rowsum[mt][r];
                s += __shfl_xor(s, 1, 64);
                s += __shfl_xor(s, 2, 64);
                s += __shfl_xor(s, 4, 64);
                s += __shfl_xor(s, 8, 64);
                rowsum[mt][r] = s;
            }
        if (l16 == 0) {
            #pragma unroll
            for (int mt = 0; mt < 4; ++mt)
                #pragma unroll
                for (int r = 0; r < 4; ++r)
                    atomicAdd(&denom[rowb + mt * 16 + q * 4 + r], rowsum[mt][r]);
        }

        u = uend;
        if (u < u1) { ++rt; snext += 256 - 8 * rt; }
    }
}

__global__ __launch_bounds__(1024) void k_finish(
    const float* __restrict__ denom, const float* __restrict__ pos,
    float* __restrict__ out)
{
    __shared__ float red[16];
    const int t = threadIdx.x;
    const int lane = t & 63, wv = t >> 6;
    float s = 0.0f;
    for (int i = t; i < NROWS; i += 1024) s += __logf(denom[i]);
    float p = 0.0f;
    for (int i = t; i < N_PAIRS; i += 1024) p += pos[i];
    float v = s - 4.0f * p;   // sum_i pos_i/T over 2N rows = 4 * sum_p cos_p
    #pragma unroll
    for (int off = 1; off < 64; off <<= 1) v += __shfl_xor(v, off, 64);
    if (lane == 0) red[wv] = v;
    __syncthreads();
    if (wv == 0) {
        float x = (lane < 16) ? red[lane] : 0.0f;
        #pragma unroll
        for (int off = 1; off < 16; off <<= 1) x += __shfl_xor(x, off, 64);
        if (lane == 0) out[0] = x / (float)NROWS;
    }
}

extern "C" void kernel_launch(void* const* d_in, const int* in_sizes, int n_in,
                              void* d_out, int out_size, void* d_ws, size_t ws_size,
                              hipStream_t stream) {
    const float* z1 = (const float*)d_in[0];
    const float* z2 = (const float*)d_in[1];
    float* out = (float*)d_out;

    char* ws = (char*)d_ws;
    __hip_bfloat16* pack = (__hip_bfloat16*)ws;                // 2 MB
    float* denom = (float*)(ws + (size_t)NROWS * ZDIM * 2);    // 32 KB
    float* pos   = denom + NROWS;                              // 16 KB

    k_normalize<<<N_PAIRS / 4, 256, 0, stream>>>(z1, z2, pack, pos, denom);
    k_simsum<<<512, 256, 0, stream>>>(pack, denom);
    k_finish<<<1, 1024, 0, stream>>>(denom, pos, out);
}